// Round 7
// baseline (224.511 us; speedup 1.0000x reference)
//
#include <hip/hip_runtime.h>
#include <stdint.h>

#define B_ 8
#define N_ 4096
#define C_ 512
#define H_ 256
#define NC_ 1000

typedef float v4f __attribute__((ext_vector_type(4)));
typedef short v8s __attribute__((ext_vector_type(8)));
typedef unsigned short ushort_t;

__device__ __forceinline__ uint32_t f2bf1(float f) {
    uint32_t u = __float_as_uint(f);
    return (u + 0x7FFFu + ((u >> 16) & 1u)) >> 16;
}
__device__ __forceinline__ uint32_t pk2(float lo, float hi) {
#if __has_builtin(__builtin_amdgcn_cvt_pk_bf16_f32)
    auto r = __builtin_amdgcn_cvt_pk_bf16_f32(lo, hi);   // v_cvt_pk_bf16_f32
    return __builtin_bit_cast(uint32_t, r);
#else
    return f2bf1(lo) | (f2bf1(hi) << 16);
#endif
}

// ---- prep: inverse permutation + proj_W -> bf16 B-fragment order + zero pooled
// Wfrag (uint4 units): slot[(ntile*16 + kb)*64 + q*16 + c] holds
// bf16(W[ntile*16+c][kb*32 + q*8 + j]), j=0..7.  (exact 524288 B)
__global__ void prep_kernel(const float* __restrict__ ps, const float* __restrict__ W,
                            int* __restrict__ inv, ushort_t* __restrict__ Wfrag,
                            float* __restrict__ pooled) {
    int blk = blockIdx.x, t = threadIdx.x;
    if (blk == 0) {  // zero pooled (later kernels accumulate with atomics)
        float4 z = {0.f, 0.f, 0.f, 0.f};
#pragma unroll
        for (int i = 0; i < 4; i++) ((float4*)pooled)[t * 4 + i] = z;
    }
    if (blk < 128) {
        int gid = blk * 256 + t;                       // 0..32767 = b*4096 + j
        float2 p = ((const float2*)ps)[gid];
        int key = (int)(p.x + 0.5f) + 64 * (int)(p.y + 0.5f);
        int b = gid >> 12;
        inv[(b << 12) + key] = gid & 4095;             // g[b, key] = feat[b, j]
    } else {
        int i = (blk - 128) * 256 + t;                 // 0..32767 = d*64 + kb*4 + q
        int d = i >> 6, kb = (i >> 2) & 15, q = i & 3;
        const float4* src = (const float4*)(W + d * C_ + kb * 32 + q * 8);
        float4 v0 = src[0], v1 = src[1];
        uint4 pk;
        pk.x = pk2(v0.x, v0.y); pk.y = pk2(v0.z, v0.w);
        pk.z = pk2(v1.x, v1.y); pk.w = pk2(v1.z, v1.w);
        ((uint4*)Wfrag)[((d >> 4) * 16 + kb) * 64 + q * 16 + (d & 15)] = pk;
    }
}

// ---- prev_pool: lean (no LDS) column-sum of prev_out, 16-deep load batches ---
__global__ __launch_bounds__(512)
void prev_pool(const float* __restrict__ prev, float* __restrict__ pooled) {
    const int t = threadIdx.x;
    const int b = blockIdx.x >> 7;
    const int r0 = (blockIdx.x & 127) << 5;            // 32-row slab
    const float* p = prev + ((size_t)(b * N_ + r0)) * C_ + t;
    float sum = 0.f;
#pragma unroll
    for (int g = 0; g < 2; g++) {
        float a[16];
#pragma unroll
        for (int j = 0; j < 16; j++) a[j] = p[(g * 16 + j) * C_];
        float s = 0.f;
#pragma unroll
        for (int j = 0; j < 16; j++) s += a[j];
        sum += s;
    }
    atomicAdd(&pooled[b * C_ + t], sum);
}

// ---- fused gather + GEMM + bias + LN + column-pool --------------------------
// WG: 64 rows x 512 cols, 8 waves. Staging: all 16 float4 loads issued before
// any pack/write (max in-flight). Epilogue: no LDS atomics (RowP partials).
__global__ __launch_bounds__(512, 4)
void gemm_ln_pool(const float* __restrict__ feat,
                  const int* __restrict__ inv, const ushort_t* __restrict__ Wfrag,
                  const float* __restrict__ pb, const float* __restrict__ lg,
                  const float* __restrict__ lb, float* __restrict__ pooled) {
    __shared__ v8s Abuf[4096];          // 64 rows x 64 chunks(16B), xor-swizzled
    __shared__ float RowP[2][8][64];    // per-wave row-stat partials
    __shared__ float RowS[64], RowQ[64], ColS[512];

    const int t = threadIdx.x;
    const int b = blockIdx.x >> 6;
    const int row0 = (blockIdx.x & 63) << 6;
    const int wv = t >> 6, lane = t & 63, c = lane & 15, q = lane >> 4;

    // ---- phase 1: stage full A tile; 16 loads in flight, then pack+write ----
    const int arow = t >> 3;                           // 0..63
    const int acol8 = t & 7;
    const int grow = inv[(b << 12) + row0 + arow];
    const float4* s4 = (const float4*)(feat + ((size_t)(b * N_ + grow) * C_));
    float4 e[8], o[8];
#pragma unroll
    for (int s = 0; s < 8; s++) {
        const int ch = s * 8 + acol8;
        e[s] = s4[ch * 2];
        o[s] = s4[ch * 2 + 1];
    }
#pragma unroll
    for (int s = 0; s < 8; s++) {
        const int ch = s * 8 + acol8;
        uint4 pk;
        pk.x = pk2(e[s].x, e[s].y); pk.y = pk2(e[s].z, e[s].w);
        pk.z = pk2(o[s].x, o[s].y); pk.w = pk2(o[s].z, o[s].w);
        ((uint4*)Abuf)[arow * 64 + (ch ^ (arow & 7))] = pk;
    }

    // B fragment bases: wave wv owns cols [64*wv, 64*wv+64), ntile = wv*4+nt
    const ushort_t* fb[4];
#pragma unroll
    for (int nt = 0; nt < 4; nt++)
        fb[nt] = Wfrag + (wv * 4 + nt) * 8192 + lane * 8;

    v4f acc[4][4];
    const v4f vzero = {0.f, 0.f, 0.f, 0.f};
#pragma unroll
    for (int mt = 0; mt < 4; mt++)
#pragma unroll
        for (int nt = 0; nt < 4; nt++) acc[mt][nt] = vzero;

    __syncthreads();

    // ---- phase 2: barrier-free K loop, only L2-hit B loads in vm queue ----
#pragma unroll 2
    for (int kb = 0; kb < 16; kb++) {
        v8s af[4], bf[4];
#pragma unroll
        for (int nt = 0; nt < 4; nt++)
            bf[nt] = *((const v8s*)(fb[nt] + kb * 512));
#pragma unroll
        for (int mt = 0; mt < 4; mt++)
            af[mt] = Abuf[(mt * 16 + c) * 64 + ((kb * 4 + q) ^ (c & 7))];
#pragma unroll
        for (int mt = 0; mt < 4; mt++)
#pragma unroll
            for (int nt = 0; nt < 4; nt++)
                acc[mt][nt] = __builtin_amdgcn_mfma_f32_16x16x32_bf16(
                    af[mt], bf[nt], acc[mt][nt], 0, 0, 0);
    }

    // ---- epilogue: bias, LN row stats (no LDS atomics), normalize, pool ----
    float pb4[4], lg4[4], lb4[4];
#pragma unroll
    for (int nt = 0; nt < 4; nt++) {
        int n = wv * 64 + nt * 16 + c;
        pb4[nt] = pb[n]; lg4[nt] = lg[n]; lb4[nt] = lb[n];
    }
#pragma unroll
    for (int mt = 0; mt < 4; mt++) {
#pragma unroll
        for (int reg = 0; reg < 4; reg++) {
            float s1 = 0.f, s2 = 0.f;
#pragma unroll
            for (int nt = 0; nt < 4; nt++) {
                float v = acc[mt][nt][reg] + pb4[nt];
                acc[mt][nt][reg] = v;
                s1 += v; s2 += v * v;
            }
#pragma unroll
            for (int d = 1; d < 16; d <<= 1) {
                s1 += __shfl_xor(s1, d);
                s2 += __shfl_xor(s2, d);
            }
            if (c == 0) {                              // 4 lanes: q = 0..3
                int r = mt * 16 + q * 4 + reg;
                RowP[0][wv][r] = s1;
                RowP[1][wv][r] = s2;
            }
        }
    }
    __syncthreads();
    if (t < 64) {
        float s1 = 0.f, s2 = 0.f;
#pragma unroll
        for (int w = 0; w < 8; w++) { s1 += RowP[0][w][t]; s2 += RowP[1][w][t]; }
        float mu = s1 * (1.f / C_);
        float var = s2 * (1.f / C_) - mu * mu;
        RowS[t] = mu;
        RowQ[t] = rsqrtf(var + 1e-5f);
    }
    __syncthreads();
    float col[4] = {0.f, 0.f, 0.f, 0.f};
#pragma unroll
    for (int mt = 0; mt < 4; mt++) {
#pragma unroll
        for (int reg = 0; reg < 4; reg++) {
            int r = mt * 16 + q * 4 + reg;
            float mu = RowS[r], rs = RowQ[r];
#pragma unroll
            for (int nt = 0; nt < 4; nt++)
                col[nt] += (acc[mt][nt][reg] - mu) * rs * lg4[nt] + lb4[nt];
        }
    }
#pragma unroll
    for (int nt = 0; nt < 4; nt++) {
        col[nt] += __shfl_xor(col[nt], 16);
        col[nt] += __shfl_xor(col[nt], 32);
    }
    if (lane < 16) {
#pragma unroll
        for (int nt = 0; nt < 4; nt++) ColS[wv * 64 + nt * 16 + c] = col[nt];
    }
    __syncthreads();
    atomicAdd(&pooled[b * C_ + t], ColS[t]);
}

// ---- head: single kernel. Each block: redundant h1,h2 (per-thread row dots,
// W1/W2 L2-hot) then a 40-output slice of layer 3 (wave-per-output). ----------
__global__ __launch_bounds__(256)
void head_kernel(const float* __restrict__ pooled,
                 const float* __restrict__ W1, const float* __restrict__ b1,
                 const float* __restrict__ W2, const float* __restrict__ b2,
                 const float* __restrict__ W3, const float* __restrict__ b3,
                 float* __restrict__ out) {
    __shared__ __align__(16) float P[512];
    __shared__ __align__(16) float H1[256];
    __shared__ __align__(16) float H2[256];
    const int t = threadIdx.x, wv = t >> 6, lane = t & 63;
    const int b = blockIdx.x / 25;
    const int slice = blockIdx.x % 25;                 // 25 slices x 40 outputs

    P[t] = pooled[b * C_ + t] * (1.f / 4096.f);
    P[t + 256] = pooled[b * C_ + t + 256] * (1.f / 4096.f);
    __syncthreads();

    {
        const float4* wr = (const float4*)(W1 + t * C_);
        float s = 0.f;
#pragma unroll 8
        for (int k = 0; k < 128; k++) {
            float4 w = wr[k];
            float4 p = ((const float4*)P)[k];
            s += w.x * p.x + w.y * p.y + w.z * p.z + w.w * p.w;
        }
        H1[t] = fmaxf(s + b1[t], 0.f);
    }
    __syncthreads();

    {
        const float4* wr = (const float4*)(W2 + t * H_);
        float s = 0.f;
#pragma unroll 8
        for (int k = 0; k < 64; k++) {
            float4 w = wr[k];
            float4 p = ((const float4*)H1)[k];
            s += w.x * p.x + w.y * p.y + w.z * p.z + w.w * p.w;
        }
        H2[t] = fmaxf(s + b2[t], 0.f);
    }
    __syncthreads();

#pragma unroll
    for (int jj = 0; jj < 10; jj++) {
        const int o = slice * 40 + jj * 4 + wv;
        float4 w = ((const float4*)(W3 + o * H_))[lane];
        float4 p = ((const float4*)H2)[lane];
        float s = w.x * p.x + w.y * p.y + w.z * p.z + w.w * p.w;
#pragma unroll
        for (int d = 1; d < 64; d <<= 1) s += __shfl_xor(s, d);
        if (lane == 0) out[b * NC_ + o] = s + b3[o];
    }
}

extern "C" void kernel_launch(void* const* d_in, const int* in_sizes, int n_in,
                              void* d_out, int out_size, void* d_ws, size_t ws_size,
                              hipStream_t stream) {
    const float* feat  = (const float*)d_in[0];
    const float* prev  = (const float*)d_in[1];
    // d_in[2] = pos_org (implicit: key(pos_org[n]) == n) — unused
    const float* ps    = (const float*)d_in[3];
    const float* projW = (const float*)d_in[4];
    const float* pb    = (const float*)d_in[5];
    const float* lg    = (const float*)d_in[6];
    const float* lb    = (const float*)d_in[7];
    const float* W1    = (const float*)d_in[8];
    const float* b1    = (const float*)d_in[9];
    const float* W2    = (const float*)d_in[10];
    const float* b2    = (const float*)d_in[11];
    const float* W3    = (const float*)d_in[12];
    const float* b3    = (const float*)d_in[13];
    float* out = (float*)d_out;

    char* ws = (char*)d_ws;
    ushort_t* Wfrag = (ushort_t*)ws;                     // 524288 B (exact)
    int* inv        = (int*)(ws + 524288);               // 131072 B
    float* pooled   = (float*)(ws + 655360);             // 16384 B

    prep_kernel<<<256, 256, 0, stream>>>(ps, projW, inv, Wfrag, pooled);
    prev_pool<<<1024, 512, 0, stream>>>(prev, pooled);
    gemm_ln_pool<<<512, 512, 0, stream>>>(feat, inv, Wfrag, pb, lg, lb, pooled);
    head_kernel<<<200, 256, 0, stream>>>(pooled, W1, b1, W2, b2, W3, b3, out);
}